// Round 2
// baseline (85.645 us; speedup 1.0000x reference)
//
#include <hip/hip_runtime.h>
#include <math.h>

#define N_ANCH 10647
#define N_GT   2048
#define N_OUTC 85
#define PRED_ELEMS (N_ANCH * N_OUTC)   // 904995
#define PRED_V4    (PRED_ELEMS / 4)    // 226248 (3 tail floats)

struct WS {
    unsigned long long akey[N_ANCH];   // packed (iou_bits<<32)|~gt_idx
    unsigned long long gkey[N_GT];     // packed (iou_bits<<32)|~anchor_idx
    unsigned int flags[N_ANCH];        // is_gt_max scatter
    float4 ac[N_ANCH];                 // anchor corners
    float  aa[N_ANCH];                 // anchor areas
    float4 gc[N_GT];                   // gt corners
    float  ga[N_GT];                   // gt areas
};

__device__ __forceinline__ float bce(float x, float t) {
    // matches: max(x,0) - x*t + log1p(exp(-|x|))
    return fmaxf(x, 0.0f) - x * t + log1pf(expf(-fabsf(x)));
}

// ---------------- K0: copy pred->out, zero keys/flags, precompute corners ----------------
__global__ __launch_bounds__(256) void k_prep(const float* __restrict__ pred,
                                              const float* __restrict__ gtb,
                                              const float* __restrict__ priors,
                                              float* __restrict__ out,
                                              WS* __restrict__ ws) {
    int idx = blockIdx.x * 256 + threadIdx.x;
    if (idx < PRED_V4)
        ((float4*)out)[idx] = ((const float4*)pred)[idx];
    if (idx == 0) {
        out[PRED_ELEMS - 3] = pred[PRED_ELEMS - 3];
        out[PRED_ELEMS - 2] = pred[PRED_ELEMS - 2];
        out[PRED_ELEMS - 1] = pred[PRED_ELEMS - 1];
    }
    if (idx < N_ANCH) {
        ws->akey[idx] = 0ull;
        ws->flags[idx] = 0u;
        float cx = priors[idx*N_OUTC+0], cy = priors[idx*N_OUTC+1];
        float w  = priors[idx*N_OUTC+2], h  = priors[idx*N_OUTC+3];
        float4 c = make_float4(cx - w*0.5f, cy - h*0.5f, cx + w*0.5f, cy + h*0.5f);
        ws->ac[idx] = c;
        ws->aa[idx] = (c.z - c.x) * (c.w - c.y);
    }
    if (idx < N_GT) {
        ws->gkey[idx] = 0ull;
        float cx = gtb[idx*4+0], cy = gtb[idx*4+1], w = gtb[idx*4+2], h = gtb[idx*4+3];
        float4 c = make_float4(cx - w*0.5f, cy - h*0.5f, cx + w*0.5f, cy + h*0.5f);
        ws->gc[idx] = c;
        ws->ga[idx] = (c.z - c.x) * (c.w - c.y);
    }
}

// ---------------- K1: fused IoU reductions ----------------
// blocks [0,672): per-anchor max/argmax. bx=b%42 (256 anchors), by=b/42 (128 GTs)
// blocks [672,1344): per-GT argmax. bx=(b-672)%8 (256 GTs), by=(b-672)/8 (128 anchors)
__global__ __launch_bounds__(256) void k_iou(WS* __restrict__ ws) {
    __shared__ float4 sc[128];
    __shared__ float  sa[128];
    int b = blockIdx.x, tx = threadIdx.x;
    if (b < 672) {
        int bx = b % 42, by = b / 42;
        int jbase = by * 128;
        if (tx < 128) { sc[tx] = ws->gc[jbase + tx]; sa[tx] = ws->ga[jbase + tx]; }
        __syncthreads();
        int i = bx * 256 + tx;
        bool valid = (i < N_ANCH);
        float4 a = make_float4(0.f, 0.f, 0.f, 0.f);
        float aa_ = 0.f;
        if (valid) { a = ws->ac[i]; aa_ = ws->aa[i]; }
        float bi = -1.0f; int bj = 0;
#pragma unroll 4
        for (int jj = 0; jj < 128; ++jj) {
            float4 g = sc[jj]; float ga_ = sa[jj];
            float lx = fmaxf(a.x, g.x), ly = fmaxf(a.y, g.y);
            float rx = fminf(a.z, g.z), ry = fminf(a.w, g.w);
            float w  = fmaxf(rx - lx, 0.0f), h = fmaxf(ry - ly, 0.0f);
            float inter = w * h;
            float iou = inter / ((aa_ + ga_) - inter);
            bool gt = iou > bi;          // strict > keeps first index on ties
            bi = gt ? iou : bi;
            bj = gt ? jj : bj;
        }
        if (valid) {
            unsigned long long key =
                ((unsigned long long)__float_as_uint(bi) << 32) |
                (unsigned)(~(unsigned)(jbase + bj));
            atomicMax(&ws->akey[i], key);
        }
    } else {
        int b2 = b - 672;
        int bx = b2 % 8, by = b2 / 8;
        int ibase = by * 128;
        if (tx < 128) {
            int i = ibase + tx;
            if (i < N_ANCH) { sc[tx] = ws->ac[i]; sa[tx] = ws->aa[i]; }
            else { sc[tx] = make_float4(0.f, 0.f, 0.f, 0.f); sa[tx] = 0.f; }
            // padded anchors give inter=0, uni=gt_area>0 -> iou=0; a real anchor
            // (iou>=0) always appears earlier in the chunk, so strict > never
            // selects the pad.
        }
        __syncthreads();
        int j = bx * 256 + tx;
        float4 g = ws->gc[j]; float ga_ = ws->ga[j];
        float bi = -1.0f; int bii = 0;
#pragma unroll 4
        for (int ii = 0; ii < 128; ++ii) {
            float4 a = sc[ii]; float aa_ = sa[ii];
            float lx = fmaxf(a.x, g.x), ly = fmaxf(a.y, g.y);
            float rx = fminf(a.z, g.z), ry = fminf(a.w, g.w);
            float w  = fmaxf(rx - lx, 0.0f), h = fmaxf(ry - ly, 0.0f);
            float inter = w * h;
            float iou = inter / ((aa_ + ga_) - inter);
            bool gt = iou > bi;
            bi = gt ? iou : bi;
            bii = gt ? ii : bii;
        }
        unsigned long long key =
            ((unsigned long long)__float_as_uint(bi) << 32) |
            (unsigned)(~(unsigned)(ibase + bii));
        atomicMax(&ws->gkey[j], key);
    }
}

// ---------------- K2: labels + demote-first + loss + finalize (1 block) ----------------
__global__ __launch_bounds__(1024) void k_tail(const float* __restrict__ pred,
                                               const float* __restrict__ gtb,
                                               const int* __restrict__ gtl,
                                               WS* __restrict__ ws,
                                               float* __restrict__ out) {
    __shared__ int w1[16], w2[16];
    __shared__ float fr[48];
    __shared__ int poslist[128];
    __shared__ int poscls[128];
    __shared__ float posbox[128][4];
    __shared__ int neglist[256];
    int tid = threadIdx.x, lane = tid & 63, wid = tid >> 6;

    // scatter is_gt_max flags
    for (int j = tid; j < N_GT; j += 1024) {
        unsigned ai = ~(unsigned)(ws->gkey[j]);
        ws->flags[ai] = 1u;
    }
    __syncthreads();

    const int NCH = (N_ANCH + 1023) / 1024;  // 11
    // pass 1: counts
    int cp = 0, cn = 0;
    for (int c = 0; c < NCH; ++c) {
        int i = c * 1024 + tid;
        if (i < N_ANCH) {
            float amax = __uint_as_float((unsigned)(ws->akey[i] >> 32));
            int lab = (amax < 0.3f) ? 0 : ((amax >= 0.7f || ws->flags[i]) ? 1 : -1);
            cp += (lab == 1); cn += (lab == 0);
        }
    }
    for (int o = 32; o; o >>= 1) { cp += __shfl_down(cp, o); cn += __shfl_down(cn, o); }
    if (lane == 0) { w1[wid] = cp; w2[wid] = cn; }
    __syncthreads();
    int npa = 0, nna = 0;
    for (int w = 0; w < 16; ++w) { npa += w1[w]; nna += w2[w]; }
    __syncthreads();

    int excess_pos = (npa > 128) ? (npa - 128) : 0;
    int n_pos_f = npa - excess_pos;
    int n_neg_req = 256 - n_pos_f;
    int excess_neg = (nna > n_neg_req) ? (nna - n_neg_req) : 0;
    int n_neg_f = nna - excess_neg;

    // pass 2: global inclusive ranks -> demote first `excess`, compact the rest
    int run_p = 0, run_n = 0;
    for (int c = 0; c < NCH; ++c) {
        int i = c * 1024 + tid;
        int lab = -2;
        if (i < N_ANCH) {
            float amax = __uint_as_float((unsigned)(ws->akey[i] >> 32));
            lab = (amax < 0.3f) ? 0 : ((amax >= 0.7f || ws->flags[i]) ? 1 : -1);
        }
        bool f1 = (lab == 1), f0 = (lab == 0);
        unsigned long long b1 = __ballot(f1), b0 = __ballot(f0);
        unsigned long long pm = (2ull << lane) - 1ull;  // inclusive mask (lane 63 ok)
        int r1 = __popcll(b1 & pm), r0 = __popcll(b0 & pm);
        if (lane == 0) { w1[wid] = __popcll(b1); w2[wid] = __popcll(b0); }
        __syncthreads();
        int p1 = 0, t1 = 0, p0 = 0, t0 = 0;
        for (int w = 0; w < 16; ++w) {
            int v1 = w1[w], v0 = w2[w];
            t1 += v1; t0 += v0;
            if (w < wid) { p1 += v1; p0 += v0; }
        }
        if (f1) {
            int cum = run_p + p1 + r1;               // inclusive cumsum, 1-based
            if (cum > excess_pos) {
                int slot = cum - excess_pos - 1;
                poslist[slot] = i;
                unsigned am = ~(unsigned)(ws->akey[i]);
                poscls[slot] = gtl[am] + 5;
                posbox[slot][0] = gtb[am*4+0];
                posbox[slot][1] = gtb[am*4+1];
                posbox[slot][2] = gtb[am*4+2];
                posbox[slot][3] = gtb[am*4+3];
            }
        }
        if (f0) {
            int cum = run_n + p0 + r0;
            if (cum > excess_neg) neglist[cum - excess_neg - 1] = i;
        }
        run_p += t1; run_n += t0;
        __syncthreads();
    }

    // loss phase
    float acc_a = 0.f, acc_c = 0.f, acc_n = 0.f;
    int nterms = n_pos_f * N_OUTC;
    for (int t = tid; t < nterms; t += 1024) {
        int pi = t / N_OUTC, col = t - pi * N_OUTC;
        int i = poslist[pi];
        float p = pred[i * N_OUTC + col];
        if (col < 4) {
            float d = p - posbox[pi][col];
            acc_a += d * d;
        } else if (col == 4) {
            acc_a += bce(p, 1.0f);
        } else {
            acc_c += bce(p, (col == poscls[pi]) ? 1.0f : 0.0f);
        }
    }
    for (int t = tid; t < n_neg_f; t += 1024) {
        acc_n += bce(pred[neglist[t] * N_OUTC + 4], 0.0f);
    }
    for (int o = 32; o; o >>= 1) {
        acc_a += __shfl_down(acc_a, o);
        acc_c += __shfl_down(acc_c, o);
        acc_n += __shfl_down(acc_n, o);
    }
    if (lane == 0) { fr[wid] = acc_a; fr[16 + wid] = acc_c; fr[32 + wid] = acc_n; }
    __syncthreads();
    if (tid == 0) {
        float A = 0.f, C = 0.f, Nn = 0.f;
        for (int w = 0; w < 16; ++w) { A += fr[w]; C += fr[16 + w]; Nn += fr[32 + w]; }
        float np = fmaxf((float)n_pos_f, 1.0f);
        float nn = fmaxf((float)n_neg_f, 1.0f);
        out[PRED_ELEMS] = A / np + Nn / nn + C / (np * 80.0f);
    }
}

extern "C" void kernel_launch(void* const* d_in, const int* in_sizes, int n_in,
                              void* d_out, int out_size, void* d_ws, size_t ws_size,
                              hipStream_t stream) {
    const float* pred   = (const float*)d_in[0];
    const float* gtb    = (const float*)d_in[1];
    const int*   gtl    = (const int*)d_in[2];
    const float* priors = (const float*)d_in[3];
    float* out = (float*)d_out;
    WS* ws = (WS*)d_ws;

    k_prep<<<dim3((PRED_V4 + 255) / 256), 256, 0, stream>>>(pred, gtb, priors, out, ws);
    k_iou<<<dim3(672 + 672), 256, 0, stream>>>(ws);
    k_tail<<<1, 1024, 0, stream>>>(pred, gtb, gtl, ws, out);
}

// Round 3
// 74.487 us; speedup vs baseline: 1.1498x; 1.1498x over previous
//
#include <hip/hip_runtime.h>
#include <math.h>

#define N_ANCH 10647
#define N_GT   2048
#define N_OUTC 85
#define PRED_ELEMS (N_ANCH * N_OUTC)   // 904995
#define PRED_V4    (PRED_ELEMS / 4)    // 226248 (3 tail floats)
#define N_CHUNK    42                  // ceil(10647/256)

struct WS {
    unsigned long long akey[N_ANCH];   // packed (iou_bits<<32)|~gt_idx
    unsigned long long gkey[N_GT];     // packed (iou_bits<<32)|~anchor_idx
    float4 ac[N_ANCH];                 // anchor corners
    float  aa[N_ANCH];                 // anchor areas
    float4 gc[N_GT];                   // gt corners
    float  ga[N_GT];                   // gt areas
    int lab[N_ANCH];                   // -1/0/1 labels (pre-demote)
    int cnt_p[N_CHUNK], cnt_n[N_CHUNK];
    int poslist[128], poscls[128];
    float4 posbox[128];
    int neglist[256];
    int counts[2];                     // n_pos_final, n_neg_final
};

__device__ __forceinline__ float bce(float x, float t) {
    // matches: max(x,0) - x*t + log1p(exp(-|x|))
    return fmaxf(x, 0.0f) - x * t + log1pf(expf(-fabsf(x)));
}

// ---------------- K0: copy pred->out, zero keys, precompute corners ----------------
__global__ __launch_bounds__(256) void k_prep(const float* __restrict__ pred,
                                              const float* __restrict__ gtb,
                                              const float* __restrict__ priors,
                                              float* __restrict__ out,
                                              WS* __restrict__ ws) {
    int idx = blockIdx.x * 256 + threadIdx.x;
    if (idx < PRED_V4)
        ((float4*)out)[idx] = ((const float4*)pred)[idx];
    if (idx == 0) {
        out[PRED_ELEMS - 3] = pred[PRED_ELEMS - 3];
        out[PRED_ELEMS - 2] = pred[PRED_ELEMS - 2];
        out[PRED_ELEMS - 1] = pred[PRED_ELEMS - 1];
    }
    if (idx < N_ANCH) {
        ws->akey[idx] = 0ull;
        float cx = priors[idx*N_OUTC+0], cy = priors[idx*N_OUTC+1];
        float w  = priors[idx*N_OUTC+2], h  = priors[idx*N_OUTC+3];
        float4 c = make_float4(cx - w*0.5f, cy - h*0.5f, cx + w*0.5f, cy + h*0.5f);
        ws->ac[idx] = c;
        ws->aa[idx] = (c.z - c.x) * (c.w - c.y);
    }
    if (idx < N_GT) {
        ws->gkey[idx] = 0ull;
        float cx = gtb[idx*4+0], cy = gtb[idx*4+1], w = gtb[idx*4+2], h = gtb[idx*4+3];
        float4 c = make_float4(cx - w*0.5f, cy - h*0.5f, cx + w*0.5f, cy + h*0.5f);
        ws->gc[idx] = c;
        ws->ga[idx] = (c.z - c.x) * (c.w - c.y);
    }
}

// ---------------- K1: fused IoU reductions ----------------
// blocks [0,672): per-anchor max/argmax. bx=b%42 (256 anchors), by=b/42 (128 GTs)
// blocks [672,1344): per-GT argmax. bx=(b-672)%8 (256 GTs), by=(b-672)/8 (128 anchors)
__global__ __launch_bounds__(256) void k_iou(WS* __restrict__ ws) {
    __shared__ float4 sc[128];
    __shared__ float  sa[128];
    int b = blockIdx.x, tx = threadIdx.x;
    if (b < 672) {
        int bx = b % 42, by = b / 42;
        int jbase = by * 128;
        if (tx < 128) { sc[tx] = ws->gc[jbase + tx]; sa[tx] = ws->ga[jbase + tx]; }
        __syncthreads();
        int i = bx * 256 + tx;
        bool valid = (i < N_ANCH);
        float4 a = make_float4(0.f, 0.f, 0.f, 0.f);
        float aa_ = 0.f;
        if (valid) { a = ws->ac[i]; aa_ = ws->aa[i]; }
        float bi = -1.0f; int bj = 0;
#pragma unroll 4
        for (int jj = 0; jj < 128; ++jj) {
            float4 g = sc[jj]; float ga_ = sa[jj];
            float lx = fmaxf(a.x, g.x), ly = fmaxf(a.y, g.y);
            float rx = fminf(a.z, g.z), ry = fminf(a.w, g.w);
            float w  = fmaxf(rx - lx, 0.0f), h = fmaxf(ry - ly, 0.0f);
            float inter = w * h;
            float iou = inter / ((aa_ + ga_) - inter);
            bool gt = iou > bi;          // strict > keeps first index on ties
            bi = gt ? iou : bi;
            bj = gt ? jj : bj;
        }
        if (valid) {
            unsigned long long key =
                ((unsigned long long)__float_as_uint(bi) << 32) |
                (unsigned)(~(unsigned)(jbase + bj));
            atomicMax(&ws->akey[i], key);
        }
    } else {
        int b2 = b - 672;
        int bx = b2 % 8, by = b2 / 8;
        int ibase = by * 128;
        if (tx < 128) {
            int i = ibase + tx;
            if (i < N_ANCH) { sc[tx] = ws->ac[i]; sa[tx] = ws->aa[i]; }
            else { sc[tx] = make_float4(0.f, 0.f, 0.f, 0.f); sa[tx] = 0.f; }
            // padded anchors give iou=0 with a later index; a real earlier
            // anchor with iou>=0 always beats them under strict >.
        }
        __syncthreads();
        int j = bx * 256 + tx;
        float4 g = ws->gc[j]; float ga_ = ws->ga[j];
        float bi = -1.0f; int bii = 0;
#pragma unroll 4
        for (int ii = 0; ii < 128; ++ii) {
            float4 a = sc[ii]; float aa_ = sa[ii];
            float lx = fmaxf(a.x, g.x), ly = fmaxf(a.y, g.y);
            float rx = fminf(a.z, g.z), ry = fminf(a.w, g.w);
            float w  = fmaxf(rx - lx, 0.0f), h = fmaxf(ry - ly, 0.0f);
            float inter = w * h;
            float iou = inter / ((aa_ + ga_) - inter);
            bool gt = iou > bi;
            bi = gt ? iou : bi;
            bii = gt ? ii : bii;
        }
        unsigned long long key =
            ((unsigned long long)__float_as_uint(bi) << 32) |
            (unsigned)(~(unsigned)(ibase + bii));
        atomicMax(&ws->gkey[j], key);
    }
}

// ---------------- K2: per-chunk labels + counts (parallel) ----------------
__global__ __launch_bounds__(256) void k_label(WS* __restrict__ ws) {
    __shared__ int flg[256];
    __shared__ int wp[4], wn[4];
    int b = blockIdx.x, t = threadIdx.x, base = b * 256;
    int lane = t & 63, wid = t >> 6;
    flg[t] = 0;
    __syncthreads();
    // rebuild is_gt_max flags for this block's anchor range
    for (int j = t; j < N_GT; j += 256) {
        int ai = (int)(~(unsigned)(ws->gkey[j]));
        int rel = ai - base;
        if ((unsigned)rel < 256u) flg[rel] = 1;   // benign same-value races
    }
    __syncthreads();
    int i = base + t;
    int lab = -2;
    if (i < N_ANCH) {
        float amax = __uint_as_float((unsigned)(ws->akey[i] >> 32));
        lab = (amax < 0.3f) ? 0 : ((amax >= 0.7f || flg[t]) ? 1 : -1);
        ws->lab[i] = lab;
    }
    unsigned long long b1 = __ballot(lab == 1), b0 = __ballot(lab == 0);
    if (lane == 0) { wp[wid] = __popcll(b1); wn[wid] = __popcll(b0); }
    __syncthreads();
    if (t == 0) {
        ws->cnt_p[b] = wp[0] + wp[1] + wp[2] + wp[3];
        ws->cnt_n[b] = wn[0] + wn[1] + wn[2] + wn[3];
    }
}

// ---------------- K3: demote-first compaction (parallel) ----------------
__global__ __launch_bounds__(256) void k_compact(const float* __restrict__ gtb,
                                                 const int* __restrict__ gtl,
                                                 WS* __restrict__ ws) {
    __shared__ int wps[4], wns[4];
    int b = blockIdx.x, t = threadIdx.x, lane = t & 63, wid = t >> 6;
    // every block redundantly computes totals + its own prefix (tiny, L2-hot)
    int npa = 0, nna = 0, pb = 0, nb = 0;
    for (int c = 0; c < N_CHUNK; ++c) {
        int cp = ws->cnt_p[c], cn = ws->cnt_n[c];
        if (c < b) { pb += cp; nb += cn; }
        npa += cp; nna += cn;
    }
    int excess_pos = (npa > 128) ? (npa - 128) : 0;
    int n_pos_f = npa - excess_pos;
    int n_neg_req = 256 - n_pos_f;
    int excess_neg = (nna > n_neg_req) ? (nna - n_neg_req) : 0;
    int n_neg_f = nna - excess_neg;

    int i = b * 256 + t;
    int lab = (i < N_ANCH) ? ws->lab[i] : -2;
    bool f1 = (lab == 1), f0 = (lab == 0);
    unsigned long long b1 = __ballot(f1), b0 = __ballot(f0);
    unsigned long long pm = (2ull << lane) - 1ull;   // inclusive mask
    int r1 = __popcll(b1 & pm), r0 = __popcll(b0 & pm);
    if (lane == 0) { wps[wid] = __popcll(b1); wns[wid] = __popcll(b0); }
    __syncthreads();
    int p1 = 0, p0 = 0;
    for (int w = 0; w < wid; ++w) { p1 += wps[w]; p0 += wns[w]; }
    if (f1) {
        int cum = pb + p1 + r1;                      // global inclusive rank
        if (cum > excess_pos) {
            int slot = cum - excess_pos - 1;
            ws->poslist[slot] = i;
            unsigned am = ~(unsigned)(ws->akey[i]);
            ws->poscls[slot] = gtl[am] + 5;
            ws->posbox[slot] = ((const float4*)gtb)[am];
        }
    }
    if (f0) {
        int cum = nb + p0 + r0;
        if (cum > excess_neg) ws->neglist[cum - excess_neg - 1] = i;
    }
    if (b == 0 && t == 0) { ws->counts[0] = n_pos_f; ws->counts[1] = n_neg_f; }
}

// ---------------- K4: loss over compacted lists ----------------
__global__ __launch_bounds__(1024) void k_loss(const float* __restrict__ pred,
                                               WS* __restrict__ ws,
                                               float* __restrict__ out) {
    __shared__ float fr[48];
    int tid = threadIdx.x, lane = tid & 63, wid = tid >> 6;
    int np = ws->counts[0], nn = ws->counts[1];
    float acc_a = 0.f, acc_c = 0.f, acc_n = 0.f;
    int nterms = np * N_OUTC;
    for (int t = tid; t < nterms; t += 1024) {
        int pi = t / N_OUTC, col = t - pi * N_OUTC;
        int i = ws->poslist[pi];
        float p = pred[i * N_OUTC + col];
        if (col < 4) {
            float d = p - ((const float*)&ws->posbox[pi])[col];
            acc_a += d * d;
        } else if (col == 4) {
            acc_a += bce(p, 1.0f);
        } else {
            acc_c += bce(p, (col == ws->poscls[pi]) ? 1.0f : 0.0f);
        }
    }
    for (int t = tid; t < nn; t += 1024) {
        acc_n += bce(pred[ws->neglist[t] * N_OUTC + 4], 0.0f);
    }
    for (int o = 32; o; o >>= 1) {
        acc_a += __shfl_down(acc_a, o);
        acc_c += __shfl_down(acc_c, o);
        acc_n += __shfl_down(acc_n, o);
    }
    if (lane == 0) { fr[wid] = acc_a; fr[16 + wid] = acc_c; fr[32 + wid] = acc_n; }
    __syncthreads();
    if (tid == 0) {
        float A = 0.f, C = 0.f, Nn = 0.f;
        for (int w = 0; w < 16; ++w) { A += fr[w]; C += fr[16 + w]; Nn += fr[32 + w]; }
        float npf = fmaxf((float)np, 1.0f);
        float nnf = fmaxf((float)nn, 1.0f);
        out[PRED_ELEMS] = A / npf + Nn / nnf + C / (npf * 80.0f);
    }
}

extern "C" void kernel_launch(void* const* d_in, const int* in_sizes, int n_in,
                              void* d_out, int out_size, void* d_ws, size_t ws_size,
                              hipStream_t stream) {
    const float* pred   = (const float*)d_in[0];
    const float* gtb    = (const float*)d_in[1];
    const int*   gtl    = (const int*)d_in[2];
    const float* priors = (const float*)d_in[3];
    float* out = (float*)d_out;
    WS* ws = (WS*)d_ws;

    k_prep<<<dim3((PRED_V4 + 255) / 256), 256, 0, stream>>>(pred, gtb, priors, out, ws);
    k_iou<<<dim3(672 + 672), 256, 0, stream>>>(ws);
    k_label<<<dim3(N_CHUNK), 256, 0, stream>>>(ws);
    k_compact<<<dim3(N_CHUNK), 256, 0, stream>>>(gtb, gtl, ws);
    k_loss<<<1, 1024, 0, stream>>>(pred, ws, out);
}